// Round 1
// baseline (412.889 us; speedup 1.0000x reference)
//
#include <hip/hip_runtime.h>

#define SEQ 2048
#define HID 2048
#define NH 16
#define HD 128
#define N1 6144   // NH * 3 * HD

typedef __attribute__((ext_vector_type(8))) short short8;
typedef __attribute__((ext_vector_type(8))) __bf16 bf16x8;
typedef __attribute__((ext_vector_type(4))) float f32x4;

__device__ __forceinline__ short f2b(float f) {
  unsigned u = __builtin_bit_cast(unsigned, f);
  unsigned r = (u + 0x7FFFu + ((u >> 16) & 1u)) >> 16;
  return (short)(r & 0xFFFFu);
}

__device__ __forceinline__ f32x4 mfma16(short8 a, short8 b, f32x4 c) {
  return __builtin_amdgcn_mfma_f32_16x16x32_bf16(
      __builtin_bit_cast(bf16x8, a), __builtin_bit_cast(bf16x8, b), c, 0, 0, 0);
}

// ---------------- cast fp32 -> bf16 bits ----------------
__global__ __launch_bounds__(256) void cast_f32_bf16(const float* __restrict__ in,
                                                     short* __restrict__ out, int n) {
  int i = (blockIdx.x * 256 + threadIdx.x) * 4;
  if (i >= n) return;
  float4 v = *reinterpret_cast<const float4*>(in + i);
  out[i + 0] = f2b(v.x);
  out[i + 1] = f2b(v.y);
  out[i + 2] = f2b(v.z);
  out[i + 3] = f2b(v.w);
}

// ---------------- transpose + cast: in fp32 [R][C] -> out bf16 [C][R] ----------------
__global__ __launch_bounds__(256) void tr_cast(const float* __restrict__ in,
                                               short* __restrict__ out, int R, int C) {
  __shared__ float t[32][33];
  int c0 = blockIdx.x * 32, r0 = blockIdx.y * 32;
  int tx = threadIdx.x, ty = threadIdx.y;  // (32, 8)
#pragma unroll
  for (int i = 0; i < 4; i++) t[ty + i * 8][tx] = in[(r0 + ty + i * 8) * C + c0 + tx];
  __syncthreads();
#pragma unroll
  for (int i = 0; i < 4; i++) out[(c0 + ty + i * 8) * R + r0 + tx] = f2b(t[tx][ty + i * 8]);
}

// ---------------- GEMM: C(MxN) = A(MxK) * Bt(NxK)^T + bias[n], fp32 out ----------------
__global__ __launch_bounds__(256) void gemm_bt(const short* __restrict__ A,
                                               const short* __restrict__ Bt,
                                               const float* __restrict__ bias,
                                               float* __restrict__ C,
                                               int M, int N, int K) {
  __shared__ __attribute__((aligned(16))) short aT[128 * 40];
  __shared__ __attribute__((aligned(16))) short bT[128 * 40];
  int tid = threadIdx.x;
  int wave = tid >> 6, lane = tid & 63;
  int lhi = lane >> 4, llo = lane & 15;
  int wr = wave >> 1, wc = wave & 1;
  int m0 = blockIdx.y * 128, n0 = blockIdx.x * 128;

  f32x4 acc[4][4];
#pragma unroll
  for (int a = 0; a < 4; a++)
#pragma unroll
    for (int b = 0; b < 4; b++) acc[a][b] = (f32x4){0.f, 0.f, 0.f, 0.f};

  for (int k0 = 0; k0 < K; k0 += 32) {
#pragma unroll
    for (int i = tid; i < 512; i += 256) {
      int r = i >> 2, kk = (i & 3) * 8;
      *(short8*)&aT[r * 40 + kk] = *(const short8*)(A + (m0 + r) * K + k0 + kk);
      *(short8*)&bT[r * 40 + kk] = *(const short8*)(Bt + (n0 + r) * K + k0 + kk);
    }
    __syncthreads();
    short8 af[4], bf[4];
#pragma unroll
    for (int mi = 0; mi < 4; mi++)
      af[mi] = *(const short8*)&aT[(wr * 64 + mi * 16 + llo) * 40 + lhi * 8];
#pragma unroll
    for (int ni = 0; ni < 4; ni++)
      bf[ni] = *(const short8*)&bT[(wc * 64 + ni * 16 + llo) * 40 + lhi * 8];
#pragma unroll
    for (int mi = 0; mi < 4; mi++)
#pragma unroll
      for (int ni = 0; ni < 4; ni++) acc[mi][ni] = mfma16(af[mi], bf[ni], acc[mi][ni]);
    __syncthreads();
  }
#pragma unroll
  for (int mi = 0; mi < 4; mi++)
#pragma unroll
    for (int ni = 0; ni < 4; ni++)
#pragma unroll
      for (int r = 0; r < 4; r++) {
        int row = m0 + wr * 64 + mi * 16 + lhi * 4 + r;
        int col = n0 + wc * 64 + ni * 16 + llo;
        C[row * (long)N + col] = acc[mi][ni][r] + bias[col];
      }
}

// ---------------- RoPE + per-head layout ----------------
// qkv fp32 [s][h*384+e]; Qb/Kb bf16 [h][s][d]; Vt bf16 [h][d][s]
__global__ __launch_bounds__(256) void rope_layout(const float* __restrict__ qkv,
                                                   short* __restrict__ Qb,
                                                   short* __restrict__ Kb,
                                                   short* __restrict__ Vt) {
  int idx = blockIdx.x * 256 + threadIdx.x;
  int d = idx & 127;
  int sh = idx >> 7;
  int h = sh & 15;
  int s = sh >> 4;
  int base = s * N1 + h * 384;
  float q = qkv[base + d];
  float k = qkv[base + 128 + d];
  float v = qkv[base + 256 + d];
  if (d < 32) {
    int i = d & 15;
    float inv_freq = powf(10000.0f, -(float)i * (1.0f / 16.0f));
    float fr = (float)s * inv_freq;
    float c, sn;
    sincosf(fr, &sn, &c);
    if (d < 16) {
      float qo = qkv[base + d + 16];
      float ko = qkv[base + 128 + d + 16];
      q = q * c - qo * sn;
      k = k * c - ko * sn;
    } else {
      float qo = qkv[base + d - 16];
      float ko = qkv[base + 128 + d - 16];
      q = q * c + qo * sn;
      k = k * c + ko * sn;
    }
  }
  int o = (h * SEQ + s) * HD + d;
  Qb[o] = f2b(q);
  Kb[o] = f2b(k);
  Vt[(h * HD + d) * SEQ + s] = f2b(v);
}

// ---------------- Flash attention (causal), per-head ----------------
// grid (S/64, NH), block 256. Output attn bf16 [s][h*128+d].
__global__ __launch_bounds__(256) void attn_kernel(const short* __restrict__ Qb,
                                                   const short* __restrict__ Kb,
                                                   const short* __restrict__ Vt,
                                                   short* __restrict__ out) {
  __shared__ __attribute__((aligned(16))) short Kt[64 * 136];
  __shared__ __attribute__((aligned(16))) short Vl[128 * 72];
  __shared__ __attribute__((aligned(16))) short Pl[4 * 16 * 72];
  const float INVNORM = 0.08838834764831845f;  // 1/sqrt(128)
  int qt = blockIdx.x, h = blockIdx.y;
  int tid = threadIdx.x;
  int wave = tid >> 6, lane = tid & 63;
  int lhi = lane >> 4, llo = lane & 15;
  int q0 = qt * 64;
  int qrow0 = q0 + wave * 16;

  // Q fragments (held for whole kernel)
  short8 qf[4];
  const short* Qbase = Qb + (h * SEQ + qrow0 + llo) * HD;
#pragma unroll
  for (int sl = 0; sl < 4; sl++) qf[sl] = *(const short8*)(Qbase + sl * 32 + lhi * 8);

  f32x4 oacc[8];
#pragma unroll
  for (int cb = 0; cb < 8; cb++) oacc[cb] = (f32x4){0.f, 0.f, 0.f, 0.f};
  float m[4], l[4];
#pragma unroll
  for (int r = 0; r < 4; r++) { m[r] = -INFINITY; l[r] = 0.f; }

  for (int t = 0; t <= qt; t++) {
    // stage K tile [64][128] -> Kt (stride 136)
#pragma unroll
    for (int i = tid; i < 1024; i += 256) {
      int r = i >> 4, seg = i & 15;
      *(short8*)&Kt[r * 136 + seg * 8] =
          *(const short8*)(Kb + (h * SEQ + t * 64 + r) * HD + seg * 8);
    }
    // stage V^T tile [128][64] -> Vl (stride 72)
#pragma unroll
    for (int i = tid; i < 1024; i += 256) {
      int dd = i >> 3, seg = i & 7;
      *(short8*)&Vl[dd * 72 + seg * 8] =
          *(const short8*)(Vt + (h * HD + dd) * SEQ + t * 64 + seg * 8);
    }
    __syncthreads();

    // S = Q K^T  (per wave: 16 q-rows x 64 k-cols)
    f32x4 sfr[4];
#pragma unroll
    for (int kb = 0; kb < 4; kb++) sfr[kb] = (f32x4){0.f, 0.f, 0.f, 0.f};
#pragma unroll
    for (int kb = 0; kb < 4; kb++)
#pragma unroll
      for (int sl = 0; sl < 4; sl++) {
        short8 bk = *(const short8*)&Kt[(kb * 16 + llo) * 136 + sl * 32 + lhi * 8];
        sfr[kb] = mfma16(qf[sl], bk, sfr[kb]);
      }

    // scale + causal mask + tile row-max
    float tmax[4];
#pragma unroll
    for (int r = 0; r < 4; r++) tmax[r] = -INFINITY;
#pragma unroll
    for (int kb = 0; kb < 4; kb++)
#pragma unroll
      for (int r = 0; r < 4; r++) {
        float sv = sfr[kb][r] * INVNORM;
        int kg = t * 64 + kb * 16 + llo;
        int qg = qrow0 + lhi * 4 + r;
        if (kg > qg) sv = -1e30f;
        sfr[kb][r] = sv;
        tmax[r] = fmaxf(tmax[r], sv);
      }
#pragma unroll
    for (int r = 0; r < 4; r++)
#pragma unroll
      for (int msk = 1; msk < 16; msk <<= 1)
        tmax[r] = fmaxf(tmax[r], __shfl_xor(tmax[r], msk));

    float psum[4];
#pragma unroll
    for (int r = 0; r < 4; r++) {
      float mn = fmaxf(m[r], tmax[r]);
      float alpha = __expf(m[r] - mn);
      m[r] = mn;
      l[r] *= alpha;
#pragma unroll
      for (int cb = 0; cb < 8; cb++) oacc[cb][r] *= alpha;
      psum[r] = 0.f;
    }
    // P = exp(S - m), write to per-wave LDS for A-fragment layout
#pragma unroll
    for (int kb = 0; kb < 4; kb++)
#pragma unroll
      for (int r = 0; r < 4; r++) {
        float p = __expf(sfr[kb][r] - m[r]);
        psum[r] += p;
        Pl[(wave * 16 + lhi * 4 + r) * 72 + kb * 16 + llo] = f2b(p);
      }
#pragma unroll
    for (int r = 0; r < 4; r++) {
#pragma unroll
      for (int msk = 1; msk < 16; msk <<= 1) psum[r] += __shfl_xor(psum[r], msk);
      l[r] += psum[r];
    }

    // O += P @ V
#pragma unroll
    for (int ks = 0; ks < 2; ks++) {
      short8 pa = *(const short8*)&Pl[(wave * 16 + llo) * 72 + ks * 32 + lhi * 8];
#pragma unroll
      for (int cb = 0; cb < 8; cb++) {
        short8 bv = *(const short8*)&Vl[(cb * 16 + llo) * 72 + ks * 32 + lhi * 8];
        oacc[cb] = mfma16(pa, bv, oacc[cb]);
      }
    }
    __syncthreads();
  }

  // epilogue: normalize and write bf16 [s][h*128+d]
#pragma unroll
  for (int cb = 0; cb < 8; cb++)
#pragma unroll
    for (int r = 0; r < 4; r++) {
      int sg = qrow0 + lhi * 4 + r;
      float val = oacc[cb][r] / l[r];
      out[sg * HID + h * HD + cb * 16 + llo] = f2b(val);
    }
}

extern "C" void kernel_launch(void* const* d_in, const int* in_sizes, int n_in,
                              void* d_out, int out_size, void* d_ws, size_t ws_size,
                              hipStream_t stream) {
  (void)in_sizes; (void)n_in; (void)out_size; (void)ws_size;
  const float* hs = (const float*)d_in[0];
  // d_in[1] = attention_mask (tril causal) — enforced structurally
  const float* w1 = (const float*)d_in[2];
  const float* b1 = (const float*)d_in[3];
  const float* w2 = (const float*)d_in[4];
  const float* b2 = (const float*)d_in[5];
  float* out = (float*)d_out;
  char* ws = (char*)d_ws;

  short* hsb   = (short*)(ws);                      // 2048*2048*2      =  8 MB
  short* w1t   = (short*)(ws + 8388608);            // 6144*2048*2      = 24 MB
  short* w2t   = (short*)(ws + 33554432);           // 2048*2048*2      =  8 MB
  float* qkvf  = (float*)(ws + 41943040);           // 2048*6144*4      = 48 MB
  short* Qb    = (short*)(ws + 92274688);           //  8 MB
  short* Kb    = (short*)(ws + 100663296);          //  8 MB
  short* Vt    = (short*)(ws + 109051904);          //  8 MB
  short* attnb = (short*)(ws + 117440512);          //  8 MB  (end 125829120)

  cast_f32_bf16<<<4096, 256, 0, stream>>>(hs, hsb, SEQ * HID);
  tr_cast<<<dim3(N1 / 32, HID / 32), dim3(32, 8), 0, stream>>>(w1, w1t, HID, N1);
  tr_cast<<<dim3(HID / 32, HID / 32), dim3(32, 8), 0, stream>>>(w2, w2t, HID, HID);
  gemm_bt<<<dim3(N1 / 128, SEQ / 128), 256, 0, stream>>>(hsb, w1t, b1, qkvf, SEQ, N1, HID);
  rope_layout<<<(SEQ * NH * HD) / 256, 256, 0, stream>>>(qkvf, Qb, Kb, Vt);
  attn_kernel<<<dim3(SEQ / 64, NH), 256, 0, stream>>>(Qb, Kb, Vt, attnb);
  gemm_bt<<<dim3(HID / 128, SEQ / 128), 256, 0, stream>>>(attnb, w2t, b2, out, SEQ, HID, HID);
}